// Round 6
// baseline (1479.886 us; speedup 1.0000x reference)
//
#include <hip/hip_runtime.h>
#include <hip/hip_bf16.h>
#include <math.h>

#define Bc 8
#define Sc 4
#define Nc 64
#define AF 133
#define BFD 147
#define Hc 300
#define BS (Bc*Sc)                  // 32
#define ROWS (BS*Nc)                // 2048 atom rows
#define EDGES (BS*Nc*Nc)            // 131072 edges
#define BSLICE 19456                // shorts per kt-slice of WP: 2*19*64*8
#define BHALF  9728                 // 19*64*8

typedef float f32x4 __attribute__((ext_vector_type(4)));
typedef short bf16x8 __attribute__((ext_vector_type(8)));
union U4 { uint4 u; bf16x8 v; };

__device__ __forceinline__ float reluf(float x){ return fmaxf(x, 0.f); }
__device__ __forceinline__ float b2f(unsigned short u){ union{unsigned int i;float f;}v; v.i = ((unsigned int)u)<<16; return v.f; }
__device__ __forceinline__ unsigned short f2b(float f){ __hip_bfloat16 h = __float2bfloat16(f); return *reinterpret_cast<unsigned short*>(&h); }
__device__ __forceinline__ void split2(float x, unsigned short &hi, unsigned short &lo){
    unsigned short h = f2b(x);
    float r = x - b2f(h);
    hi = h; lo = f2b(r);
}

// ---------------- K1: input_atom = relu(f_atoms @ W_i_atom); message_atom = copy (fp32 VALU)
__global__ __launch_bounds__(320) void k_atom_embed(const float* __restrict__ f_atoms,
        const float* __restrict__ W, float* __restrict__ input_atom, float* __restrict__ message_atom){
    __shared__ float x[AF];
    int row = blockIdx.x;
    const float* fr = f_atoms + (size_t)row*AF;
    for (int d = threadIdx.x; d < AF; d += blockDim.x) x[d] = fr[d];
    __syncthreads();
    int h = threadIdx.x;
    if (h < Hc){
        float acc = 0.f;
        for (int d = 0; d < AF; ++d) acc = fmaf(x[d], W[d*Hc + h], acc);
        float v = reluf(acc);
        input_atom[(size_t)row*Hc + h] = v;
        message_atom[(size_t)row*Hc + h] = v;
    }
}

// ---------------- prep (merged): W [K][300] -> split bf16, layout [kt][hi/lo][19 ct][64 lane][8]
// blocks [0,760): W_h0 ; [760,1520): W_h1 ; [1520,1900): W_i_bond (K=147, NKT=5)
__global__ __launch_bounds__(256) void k_prep_all(
        const float* __restrict__ W0, const float* __restrict__ W1, const float* __restrict__ Wb,
        unsigned short* __restrict__ WP0, unsigned short* __restrict__ WP1,
        unsigned short* __restrict__ WPb){
    int blk = blockIdx.x;
    const float* W; unsigned short* WP; int K, base;
    if (blk < 760)      { W = W0; WP = WP0; K = Hc;  base = blk; }
    else if (blk < 1520){ W = W1; WP = WP1; K = Hc;  base = blk - 760; }
    else                { W = Wb; WP = WPb; K = BFD; base = blk - 1520; }
    int idx = base*256 + threadIdx.x;
    int j  = idx & 7;
    int l  = (idx >> 3) & 63;
    int ct = (idx >> 9) % 19;
    int rem = idx / BHALF;
    int hl = rem & 1;
    int kt = rem >> 1;
    int col = ct*16 + (l & 15);
    int k   = kt*32 + (l >> 4)*8 + j;
    float v = (col < Hc && k < K) ? W[k*Hc + col] : 0.f;
    unsigned short hi, lo; split2(v, hi, lo);
    WP[idx] = hl ? lo : hi;
}

// ---------------- tiled split-bf16 MFMA edge GEMM (128 rows x 304 cols per block)
// MODE 0: dst = relu((adj*f_bonds) @ W_i_bond)      (plain row blocks, K=147)
// MODE 1: dst[eo] = relu(ib[eo] + A @ W_h)*sm[eo]   (closed-pair blocks; in-place safe)
//         A-row for output edge (a,b): adj[(b,a)]*ma[a,:] - mb_old[(b,a),:]
// sA double-buffered: per kt, barrier#1 drains only L2-hot copyB loads; prefetchA gets a
// full compute phase of slack before buildA's waitcnt; barrier#2 drains only LDS writes.
template<int MODE>
__global__ __launch_bounds__(1024, 8) void k_gemm_t(
        const float* __restrict__ Asrc,          // MODE0: f_bonds [E][147]; MODE1: mb_old [E][300]
        const unsigned short* __restrict__ WP,   // [NKT][2][19][64][8]
        const float* __restrict__ ma,
        const float* __restrict__ adj,
        const float* __restrict__ sm,
        const float* __restrict__ ib,
        float* __restrict__ dst)
{
    constexpr int NKT  = MODE ? 10 : 5;
    constexpr int ASTR = MODE ? 300 : BFD;

    __shared__ unsigned short sA[2][2][4096];    // [buf][hi/lo][128 rows x 32 k chunked]
    __shared__ unsigned short sB[BSLICE];        // hi block then lo block
    __shared__ int s_eOut[128];
    __shared__ int s_eRev[128];
    __shared__ float s_adjRev[128];
    __shared__ int s_aAtom[128];

    const int t = threadIdx.x;
    if (MODE){
        if (t < 128){
            int r = t;
            int bs = blockIdx.x >> 5, kk = blockIdx.x & 31;
            int s1 = 64-kk, s2 = 127-2*kk, s3 = 128-kk;
            int a, b;
            if (r < s1){ a = kk; b = kk + r; }
            else if (r < s2){ a = kk+1 + (r - s1); b = kk; }
            else if (r < s3){ a = 63-kk; b = 63-kk + (r - s2); }
            else { a = 64-kk + (r - s3); b = 63-kk; }
            int eo = (bs*64 + a)*64 + b;
            int er = (bs*64 + b)*64 + a;
            s_eOut[r] = eo; s_eRev[r] = er; s_aAtom[r] = bs*64 + a;
            s_adjRev[r] = adj[er];
        }
        __syncthreads();
    }

    // ---- A-build role: thread t -> row brow, k-offset koff (4 floats), LDS shorts [4t..4t+3]
    const int rt_b = t >> 7;
    const int q_b  = (t >> 5) & 3;
    const int li_b = (t >> 1) & 15;
    const int half = t & 1;
    const int brow = rt_b*16 + li_b;
    const int koff = q_b*8 + 4*half;
    const float* aRow;
    const float* mRow = nullptr;
    float adjR = 0.f;
    if (MODE){
        aRow = Asrc + (size_t)s_eRev[brow]*ASTR;
        mRow = ma + (size_t)s_aAtom[brow]*Hc;
        adjR = s_adjRev[brow];
    } else {
        int e = blockIdx.x*128 + brow;
        aRow = Asrc + (size_t)e*ASTR;
        adjR = adj[e];
    }

    float pm[4], pa[4];
    auto prefetchA = [&](int kt){
        int k0 = kt*32 + koff;
        if (MODE){
            if (k0 <= 296){
                float4 v = *(const float4*)(aRow + k0);
                float4 w = *(const float4*)(mRow + k0);
                pm[0]=v.x; pm[1]=v.y; pm[2]=v.z; pm[3]=v.w;
                pa[0]=w.x; pa[1]=w.y; pa[2]=w.z; pa[3]=w.w;
            }
        } else {
            #pragma unroll
            for (int j = 0; j < 4; ++j){
                int k = k0 + j;
                pm[j] = (k < BFD) ? aRow[k] : 0.f;
            }
        }
    };
    auto buildA = [&](int kt, int buf){
        int k0 = kt*32 + koff;
        float xv[4];
        if (MODE){
            if (k0 <= 296){
                #pragma unroll
                for (int j = 0; j < 4; ++j) xv[j] = fmaf(adjR, pa[j], -pm[j]);
            } else { xv[0]=xv[1]=xv[2]=xv[3]=0.f; }
        } else {
            #pragma unroll
            for (int j = 0; j < 4; ++j) xv[j] = adjR * pm[j];
        }
        unsigned short h0,l0,h1,l1,h2,l2,h3,l3;
        split2(xv[0],h0,l0); split2(xv[1],h1,l1);
        split2(xv[2],h2,l2); split2(xv[3],h3,l3);
        uint2 hw, lw;
        hw.x = (unsigned int)h0 | ((unsigned int)h1<<16);
        hw.y = (unsigned int)h2 | ((unsigned int)h3<<16);
        lw.x = (unsigned int)l0 | ((unsigned int)l1<<16);
        lw.y = (unsigned int)l2 | ((unsigned int)l3<<16);
        *(uint2*)&sA[buf][0][4*t] = hw;          // byte 8t: bank-linear, conflict-free
        *(uint2*)&sA[buf][1][4*t] = lw;
    };
    auto copyB = [&](int kt){
        const unsigned short* src = WP + (size_t)kt*BSLICE;
        #pragma unroll
        for (int rep = 0; rep < 3; ++rep){
            int i = t + rep*1024;
            if (i < BSLICE/8){
                uint4 v = *(const uint4*)(src + i*8);
                *(uint4*)&sB[i*8] = v;
            }
        }
    };

    // ---- compute role
    const int wv = t >> 6, lane = t & 63;
    const int li = lane & 15, quad = lane >> 4;
    const int rg = wv & 3;                       // row-tiles 2rg, 2rg+1
    const int cg = wv >> 2;
    const int c0 = cg*5;
    const int myC = (cg < 3) ? 5 : 4;

    f32x4 acc[5][2];
    #pragma unroll
    for (int c = 0; c < 5; ++c){ acc[c][0] = (f32x4){0,0,0,0}; acc[c][1] = (f32x4){0,0,0,0}; }

    prefetchA(0);
    buildA(0, 0);
    for (int kt = 0; kt < NKT; ++kt){
        copyB(kt);
        __syncthreads();                         // #1: sB(kt)+sA(kt) visible; drains L2-hot copyB only
        if (kt+1 < NKT) prefetchA(kt+1);         // HBM loads get a full compute phase of slack
        const int buf = kt & 1;
        U4 a0h, a0l, a1h, a1l;
        a0h.u = *(const uint4*)&sA[buf][0][((2*rg  )*64 + lane)*8];
        a0l.u = *(const uint4*)&sA[buf][1][((2*rg  )*64 + lane)*8];
        a1h.u = *(const uint4*)&sA[buf][0][((2*rg+1)*64 + lane)*8];
        a1l.u = *(const uint4*)&sA[buf][1][((2*rg+1)*64 + lane)*8];
        #pragma unroll
        for (int c = 0; c < 5; ++c){
            if (c < myC){
                U4 bh, bl;
                bh.u = *(const uint4*)&sB[        (c0+c)*512 + lane*8];
                bl.u = *(const uint4*)&sB[BHALF + (c0+c)*512 + lane*8];
                acc[c][0] = __builtin_amdgcn_mfma_f32_16x16x32_bf16(a0h.v, bl.v, acc[c][0], 0,0,0);
                acc[c][0] = __builtin_amdgcn_mfma_f32_16x16x32_bf16(a0l.v, bh.v, acc[c][0], 0,0,0);
                acc[c][0] = __builtin_amdgcn_mfma_f32_16x16x32_bf16(a0h.v, bh.v, acc[c][0], 0,0,0);
                acc[c][1] = __builtin_amdgcn_mfma_f32_16x16x32_bf16(a1h.v, bl.v, acc[c][1], 0,0,0);
                acc[c][1] = __builtin_amdgcn_mfma_f32_16x16x32_bf16(a1l.v, bh.v, acc[c][1], 0,0,0);
                acc[c][1] = __builtin_amdgcn_mfma_f32_16x16x32_bf16(a1h.v, bh.v, acc[c][1], 0,0,0);
            }
        }
        if (kt+1 < NKT){
            buildA(kt+1, (kt+1)&1);              // waitcnt here: loads issued ~compute-phase ago
            __syncthreads();                     // #2: drains LDS writes only (fast)
        }
    }

    // ---- epilogue (in-place safe: all global A-reads drained before iter NKT-2's barrier #2)
    int eO[2][4]; float smv[2][4];
    #pragma unroll
    for (int r2 = 0; r2 < 2; ++r2)
        #pragma unroll
        for (int i = 0; i < 4; ++i){
            int row = (2*rg + r2)*16 + quad*4 + i;
            int e = MODE ? s_eOut[row] : blockIdx.x*128 + row;
            eO[r2][i] = e;
            if (MODE) smv[r2][i] = sm[e];
        }
    #pragma unroll
    for (int c = 0; c < 5; ++c){
        if (c >= myC) continue;
        int h = (c0 + c)*16 + li;
        if (h >= Hc) continue;
        #pragma unroll
        for (int r2 = 0; r2 < 2; ++r2)
            #pragma unroll
            for (int i = 0; i < 4; ++i){
                size_t off = (size_t)eO[r2][i]*Hc + h;
                float v = acc[c][r2][i];
                if (MODE) v = reluf(v + ib[off]) * smv[r2][i];
                else      v = reluf(v);
                dst[off] = v;
            }
    }
}

// ---------------- K3: agg[bs,m,h] = (sum_n mb[n,m,h]) * sigmoid(max_n mb[n,m,h])  (fp32)
__global__ __launch_bounds__(320) void k_agg(const float* __restrict__ message_bond,
        float* __restrict__ message_atom, float* __restrict__ agg_out, int final_mode){
    int row = blockIdx.x;           // bs*64 + m
    int bs = row >> 6, m = row & 63;
    int h = threadIdx.x;
    if (h >= Hc) return;
    size_t base = ((size_t)(bs*Nc)*Nc + m)*(size_t)Hc + h;
    float s = 0.f, mx = -INFINITY;
    #pragma unroll 8
    for (int n = 0; n < Nc; ++n){
        float v = message_bond[base + (size_t)n*Nc*Hc];
        s += v; mx = fmaxf(mx, v);
    }
    float agg = s * (1.f/(1.f + expf(-mx)));
    if (final_mode) agg_out[(size_t)row*Hc + h] = agg;
    else message_atom[(size_t)row*Hc + h] += agg;
}

// ---------------- K4: res[n,m] = dot(ma[n],ma[m])*adj[n,m]; sm = softmax over n per (b,s,m)
__global__ __launch_bounds__(256) void k_resonance_softmax(const float* __restrict__ message_atom,
        const float* __restrict__ adj, float* __restrict__ sm){
    int bs = blockIdx.x >> 6, m = blockIdx.x & 63;
    __shared__ float am[Hc];
    __shared__ float res[Nc];
    for (int d = threadIdx.x; d < Hc; d += blockDim.x)
        am[d] = message_atom[((size_t)(bs*Nc)+m)*Hc + d];
    __syncthreads();
    int wave = threadIdx.x >> 6, lane = threadIdx.x & 63;
    for (int n = wave; n < Nc; n += 4){
        const float* man = message_atom + ((size_t)(bs*Nc)+n)*Hc;
        float acc = 0.f;
        for (int d = lane; d < Hc; d += 64) acc = fmaf(man[d], am[d], acc);
        #pragma unroll
        for (int off = 32; off > 0; off >>= 1) acc += __shfl_xor(acc, off, 64);
        if (lane == 0) res[n] = acc * adj[((size_t)(bs*Nc)+n)*Nc + m];
    }
    __syncthreads();
    if (threadIdx.x < Nc){
        float v = res[threadIdx.x];
        float mx = v;
        #pragma unroll
        for (int off = 32; off > 0; off >>= 1) mx = fmaxf(mx, __shfl_xor(mx, off, 64));
        float e = expf(v - mx);
        float ssum = e;
        #pragma unroll
        for (int off = 32; off > 0; off >>= 1) ssum += __shfl_xor(ssum, off, 64);
        sm[((size_t)(bs*Nc)+threadIdx.x)*Nc + m] = e / ssum;
    }
}

// ---------------- K6: atom_hiddens = relu([agg|message_atom|input_atom] @ W_o + b_o)
#define R7 4
__global__ __launch_bounds__(320) void k_output(const float* __restrict__ agg,
        const float* __restrict__ message_atom, const float* __restrict__ input_atom,
        const float* __restrict__ W_o, const float* __restrict__ b_o, float* __restrict__ out){
    __shared__ float xin[R7][3*Hc];
    int r0 = blockIdx.x * R7;
    for (int idx = threadIdx.x; idx < R7*3*Hc; idx += blockDim.x){
        int r = idx / (3*Hc), k = idx - r*(3*Hc);
        int row = r0 + r;
        float v;
        if (k < Hc)           v = agg[(size_t)row*Hc + k];
        else if (k < 2*Hc)    v = message_atom[(size_t)row*Hc + (k - Hc)];
        else                  v = input_atom[(size_t)row*Hc + (k - 2*Hc)];
        xin[r][k] = v;
    }
    __syncthreads();
    int h = threadIdx.x;
    if (h < Hc){
        float acc[R7];
        #pragma unroll
        for (int r=0;r<R7;r++) acc[r] = b_o[h];
        for (int d = 0; d < 3*Hc; ++d){
            float w = W_o[d*Hc + h];
            #pragma unroll
            for (int r=0;r<R7;r++) acc[r] = fmaf(xin[r][d], w, acc[r]);
        }
        #pragma unroll
        for (int r=0;r<R7;r++) out[(size_t)(r0+r)*Hc + h] = reluf(acc[r]);
    }
}

extern "C" void kernel_launch(void* const* d_in, const int* in_sizes, int n_in,
                              void* d_out, int out_size, void* d_ws, size_t ws_size,
                              hipStream_t stream){
    const float* f_atoms  = (const float*)d_in[0];
    const float* f_bonds  = (const float*)d_in[1];
    const float* adj      = (const float*)d_in[2];
    const float* W_i_atom = (const float*)d_in[3];
    const float* W_i_bond = (const float*)d_in[4];
    const float* W_h0     = (const float*)d_in[5];
    const float* W_h1     = (const float*)d_in[6];
    const float* W_o      = (const float*)d_in[7];
    const float* b_o      = (const float*)d_in[8];

    float* out = (float*)d_out;
    float* atom_hiddens = out;                       // [2048, 300]
    float* mb_out = out + (size_t)ROWS*Hc;           // [131072, 300] fp32 (output #2)

    float* wsf = (float*)d_ws;
    float* input_atom   = wsf; wsf += (size_t)ROWS*Hc;
    float* message_atom = wsf; wsf += (size_t)ROWS*Hc;
    float* sm           = wsf; wsf += (size_t)EDGES;
    float* ib           = wsf; wsf += (size_t)EDGES*Hc;         // 39.3M floats
    unsigned short* wsu = (unsigned short*)wsf;
    unsigned short* WP0 = wsu; wsu += 10*BSLICE;
    unsigned short* WP1 = wsu; wsu += 10*BSLICE;
    unsigned short* WPb = wsu; wsu += 5*BSLICE;
    float* agg_out = ib;   // alias: ib dead after step-2 GEMM

    k_atom_embed<<<ROWS, 320, 0, stream>>>(f_atoms, W_i_atom, input_atom, message_atom);
    k_prep_all<<<1900, 256, 0, stream>>>(W_h0, W_h1, W_i_bond, WP0, WP1, WPb);
    // bond embed (fused adj*f_bonds): ib = relu((adj*f_bonds) @ W_i_bond)
    k_gemm_t<0><<<EDGES/128, 1024, 0, stream>>>(f_bonds, WPb, nullptr, adj, nullptr, nullptr, ib);
    // step 1: mb_old = ib -> mb_out (out-of-place)
    k_agg<<<ROWS, 320, 0, stream>>>(ib, message_atom, nullptr, 0);
    k_resonance_softmax<<<ROWS, 256, 0, stream>>>(message_atom, adj, sm);
    k_gemm_t<1><<<BS*32, 1024, 0, stream>>>(ib, WP0, message_atom, adj, sm, ib, mb_out);
    // step 2: mb_old = mb_out -> mb_out (in-place via closed-pair blocks)
    k_agg<<<ROWS, 320, 0, stream>>>(mb_out, message_atom, nullptr, 0);
    k_resonance_softmax<<<ROWS, 256, 0, stream>>>(message_atom, adj, sm);
    k_gemm_t<1><<<BS*32, 1024, 0, stream>>>(mb_out, WP1, message_atom, adj, sm, ib, mb_out);
    // final aggregate + output layer
    k_agg<<<ROWS, 320, 0, stream>>>(mb_out, nullptr, agg_out, 1);
    k_output<<<ROWS/R7, 320, 0, stream>>>(agg_out, message_atom, input_atom, W_o, b_o, atom_hiddens);
}

// Round 7
// 825.938 us; speedup vs baseline: 1.7918x; 1.7918x over previous
//
#include <hip/hip_runtime.h>
#include <hip/hip_bf16.h>
#include <math.h>

#define Bc 8
#define Sc 4
#define Nc 64
#define AF 133
#define BFD 147
#define Hc 300
#define BS (Bc*Sc)                  // 32
#define ROWS (BS*Nc)                // 2048 atom rows
#define EDGES (BS*Nc*Nc)            // 131072 edges
#define BSLICE 19456                // shorts per kt-slice of WP: 2*19*64*8
#define BHALF  9728                 // 19*64*8

typedef float f32x4 __attribute__((ext_vector_type(4)));
typedef short bf16x8 __attribute__((ext_vector_type(8)));
union U4 { uint4 u; bf16x8 v; };

__device__ __forceinline__ float reluf(float x){ return fmaxf(x, 0.f); }
__device__ __forceinline__ float b2f(unsigned short u){ union{unsigned int i;float f;}v; v.i = ((unsigned int)u)<<16; return v.f; }
__device__ __forceinline__ unsigned short f2b(float f){ __hip_bfloat16 h = __float2bfloat16(f); return *reinterpret_cast<unsigned short*>(&h); }
__device__ __forceinline__ void split2(float x, unsigned short &hi, unsigned short &lo){
    unsigned short h = f2b(x);
    float r = x - b2f(h);
    hi = h; lo = f2b(r);
}

// ---------------- K1: input_atom = relu(f_atoms @ W_i_atom); message_atom = copy (fp32 VALU)
__global__ __launch_bounds__(320) void k_atom_embed(const float* __restrict__ f_atoms,
        const float* __restrict__ W, float* __restrict__ input_atom, float* __restrict__ message_atom){
    __shared__ float x[AF];
    int row = blockIdx.x;
    const float* fr = f_atoms + (size_t)row*AF;
    for (int d = threadIdx.x; d < AF; d += blockDim.x) x[d] = fr[d];
    __syncthreads();
    int h = threadIdx.x;
    if (h < Hc){
        float acc = 0.f;
        for (int d = 0; d < AF; ++d) acc = fmaf(x[d], W[d*Hc + h], acc);
        float v = reluf(acc);
        input_atom[(size_t)row*Hc + h] = v;
        message_atom[(size_t)row*Hc + h] = v;
    }
}

// ---------------- prep (merged): W [K][300] -> split bf16, layout [kt][hi/lo][19 ct][64 lane][8]
__global__ __launch_bounds__(256) void k_prep_all(
        const float* __restrict__ W0, const float* __restrict__ W1, const float* __restrict__ Wb,
        unsigned short* __restrict__ WP0, unsigned short* __restrict__ WP1,
        unsigned short* __restrict__ WPb){
    int blk = blockIdx.x;
    const float* W; unsigned short* WP; int K, base;
    if (blk < 760)      { W = W0; WP = WP0; K = Hc;  base = blk; }
    else if (blk < 1520){ W = W1; WP = WP1; K = Hc;  base = blk - 760; }
    else                { W = Wb; WP = WPb; K = BFD; base = blk - 1520; }
    int idx = base*256 + threadIdx.x;
    int j  = idx & 7;
    int l  = (idx >> 3) & 63;
    int ct = (idx >> 9) % 19;
    int rem = idx / BHALF;
    int hl = rem & 1;
    int kt = rem >> 1;
    int col = ct*16 + (l & 15);
    int k   = kt*32 + (l >> 4)*8 + j;
    float v = (col < Hc && k < K) ? W[k*Hc + col] : 0.f;
    unsigned short hi, lo; split2(v, hi, lo);
    WP[idx] = hl ? lo : hi;
}

// ---------------- tiled split-bf16 MFMA edge GEMM (128 rows x 304 cols per block)
// MODE 0: ib = relu((adj*f_bonds) @ W_i_bond)                row blocks
// MODE 1: mb1T[er] = relu(ib[eo] + A @ W_h0)*sm[eo]          pair blocks (A-row: adj[er]*ma[a]-ib[er])
//         (output for edge eo=(a,b) stored TRANSPOSED at row er=(b,a))
// MODE 2: mb[e] = relu(ib[e] + A @ W_h1)*sm[e]               row blocks, A-row: adj[rev]*ma[a]-mb1T[e]
//         (mb1T read & mb written in the SAME buffer, row-local -> in-place safe)
template<int MODE>
__global__ __launch_bounds__(1024) void k_gemm_t(
        const float* __restrict__ Asrc,          // M0: f_bonds [E][147]; M1: ib [E][300]; M2: mb1T [E][300]
        const unsigned short* __restrict__ WP,   // [NKT][2][19][64][8]
        const float* __restrict__ ma,
        const float* __restrict__ adj,
        const float* __restrict__ sm,
        const float* __restrict__ ib,
        float* __restrict__ dst)
{
    constexpr int NKT  = (MODE==0) ? 5 : 10;
    constexpr int ASTR = (MODE==0) ? BFD : 300;

    __shared__ unsigned short sA[2][2][4096];    // [buf][hi/lo][128 rows x 32 k chunked]
    __shared__ unsigned short sB[BSLICE];        // hi block then lo block
    __shared__ int s_eOut[128];
    __shared__ int s_eRev[128];
    __shared__ float s_adjRev[128];
    __shared__ int s_aAtom[128];

    const int t = threadIdx.x;
    if (MODE == 1){
        if (t < 128){
            int r = t;
            int bs = blockIdx.x >> 5, kk = blockIdx.x & 31;
            int s1 = 64-kk, s2 = 127-2*kk, s3 = 128-kk;
            int a, b;
            if (r < s1){ a = kk; b = kk + r; }
            else if (r < s2){ a = kk+1 + (r - s1); b = kk; }
            else if (r < s3){ a = 63-kk; b = 63-kk + (r - s2); }
            else { a = 64-kk + (r - s3); b = 63-kk; }
            int eo = (bs*64 + a)*64 + b;
            int er = (bs*64 + b)*64 + a;
            s_eOut[r] = eo; s_eRev[r] = er; s_aAtom[r] = bs*64 + a;
            s_adjRev[r] = adj[er];
        }
        __syncthreads();
    }

    // ---- A-build role: thread t -> row brow, k-offset koff (4 floats), LDS shorts [4t..4t+3]
    const int rt_b = t >> 7;
    const int q_b  = (t >> 5) & 3;
    const int li_b = (t >> 1) & 15;
    const int half = t & 1;
    const int brow = rt_b*16 + li_b;
    const int koff = q_b*8 + 4*half;
    const float* aRow;
    const float* mRow = nullptr;
    float adjR;
    if (MODE == 1){
        aRow = Asrc + (size_t)s_eRev[brow]*ASTR;
        mRow = ma + (size_t)s_aAtom[brow]*Hc;
        adjR = s_adjRev[brow];
    } else if (MODE == 2){
        int e = blockIdx.x*128 + brow;
        int bs = e >> 12, a = (e >> 6) & 63, b = e & 63;
        int rev = (bs*64 + b)*64 + a;
        aRow = Asrc + (size_t)e*ASTR;
        mRow = ma + (size_t)(bs*64 + a)*Hc;
        adjR = adj[rev];
    } else {
        int e = blockIdx.x*128 + brow;
        aRow = Asrc + (size_t)e*ASTR;
        adjR = adj[e];
    }

    float pA[2][4];          // depth-2 prefetch of the HBM A-stream
    float pM[4];             // depth-1 prefetch of L2-hot ma
    auto prefA = [&](int kt, int buf){
        int k0 = kt*32 + koff;
        if (MODE == 0){
            #pragma unroll
            for (int j = 0; j < 4; ++j){
                int k = k0 + j;
                pA[buf][j] = (k < BFD) ? aRow[k] : 0.f;
            }
        } else {
            if (k0 <= 296){
                float4 v = *(const float4*)(aRow + k0);
                pA[buf][0]=v.x; pA[buf][1]=v.y; pA[buf][2]=v.z; pA[buf][3]=v.w;
            }
        }
    };
    auto prefM = [&](int kt){
        if (MODE == 0) return;
        int k0 = kt*32 + koff;
        if (k0 <= 296){
            float4 w = *(const float4*)(mRow + k0);
            pM[0]=w.x; pM[1]=w.y; pM[2]=w.z; pM[3]=w.w;
        }
    };
    auto buildA = [&](int kt, int buf){
        int k0 = kt*32 + koff;
        float xv[4];
        if (MODE == 0){
            #pragma unroll
            for (int j = 0; j < 4; ++j) xv[j] = adjR * pA[buf][j];
        } else {
            if (k0 <= 296){
                #pragma unroll
                for (int j = 0; j < 4; ++j) xv[j] = fmaf(adjR, pM[j], -pA[buf][j]);
            } else { xv[0]=xv[1]=xv[2]=xv[3]=0.f; }
        }
        unsigned short h0,l0,h1,l1,h2,l2,h3,l3;
        split2(xv[0],h0,l0); split2(xv[1],h1,l1);
        split2(xv[2],h2,l2); split2(xv[3],h3,l3);
        uint2 hw, lw;
        hw.x = (unsigned int)h0 | ((unsigned int)h1<<16);
        hw.y = (unsigned int)h2 | ((unsigned int)h3<<16);
        lw.x = (unsigned int)l0 | ((unsigned int)l1<<16);
        lw.y = (unsigned int)l2 | ((unsigned int)l3<<16);
        *(uint2*)&sA[buf][0][4*t] = hw;          // byte 8t: bank-linear, conflict-free
        *(uint2*)&sA[buf][1][4*t] = lw;
    };
    auto copyB = [&](int kt){
        const unsigned short* src = WP + (size_t)kt*BSLICE;
        #pragma unroll
        for (int rep = 0; rep < 3; ++rep){
            int i = t + rep*1024;
            if (i < BSLICE/8){
                uint4 v = *(const uint4*)(src + i*8);
                *(uint4*)&sB[i*8] = v;
            }
        }
    };

    // ---- compute role
    const int wv = t >> 6, lane = t & 63;
    const int li = lane & 15, quad = lane >> 4;
    const int rg = wv & 3;                       // row-tiles 2rg, 2rg+1
    const int cg = wv >> 2;
    const int c0 = cg*5;
    const int myC = (cg < 3) ? 5 : 4;

    f32x4 acc[5][2];
    #pragma unroll
    for (int c = 0; c < 5; ++c){ acc[c][0] = (f32x4){0,0,0,0}; acc[c][1] = (f32x4){0,0,0,0}; }

    prefA(0, 0);
    prefA(1, 1);
    prefM(0);
    buildA(0, 0);
    for (int kt = 0; kt < NKT; ++kt){
        copyB(kt);
        __syncthreads();                         // sB(kt)+sA(kt) visible
        if (kt+2 < NKT) prefA(kt+2, kt & 1);     // 2 compute phases of slack for HBM
        if (kt+1 < NKT) prefM(kt+1);             // 1 phase, L2-hot
        const int buf = kt & 1;
        U4 a0h, a0l, a1h, a1l;
        a0h.u = *(const uint4*)&sA[buf][0][((2*rg  )*64 + lane)*8];
        a0l.u = *(const uint4*)&sA[buf][1][((2*rg  )*64 + lane)*8];
        a1h.u = *(const uint4*)&sA[buf][0][((2*rg+1)*64 + lane)*8];
        a1l.u = *(const uint4*)&sA[buf][1][((2*rg+1)*64 + lane)*8];
        #pragma unroll
        for (int c = 0; c < 5; ++c){
            if (c < myC){
                U4 bh, bl;
                bh.u = *(const uint4*)&sB[        (c0+c)*512 + lane*8];
                bl.u = *(const uint4*)&sB[BHALF + (c0+c)*512 + lane*8];
                acc[c][0] = __builtin_amdgcn_mfma_f32_16x16x32_bf16(a0h.v, bl.v, acc[c][0], 0,0,0);
                acc[c][0] = __builtin_amdgcn_mfma_f32_16x16x32_bf16(a0l.v, bh.v, acc[c][0], 0,0,0);
                acc[c][0] = __builtin_amdgcn_mfma_f32_16x16x32_bf16(a0h.v, bh.v, acc[c][0], 0,0,0);
                acc[c][1] = __builtin_amdgcn_mfma_f32_16x16x32_bf16(a1h.v, bl.v, acc[c][1], 0,0,0);
                acc[c][1] = __builtin_amdgcn_mfma_f32_16x16x32_bf16(a1l.v, bh.v, acc[c][1], 0,0,0);
                acc[c][1] = __builtin_amdgcn_mfma_f32_16x16x32_bf16(a1h.v, bh.v, acc[c][1], 0,0,0);
            }
        }
        if (kt+1 < NKT){
            buildA(kt+1, (kt+1)&1);              // pA loaded 2 phases ago; pM 1 phase ago
            __syncthreads();                     // drains LDS writes only
        }
    }

    // ---- epilogue
    int eB[2][4];   // bias/sm row (logical output edge)
    int eW[2][4];   // write row in dst
    float smv[2][4];
    #pragma unroll
    for (int r2 = 0; r2 < 2; ++r2)
        #pragma unroll
        for (int i = 0; i < 4; ++i){
            int row = (2*rg + r2)*16 + quad*4 + i;
            if (MODE == 1){
                eB[r2][i] = s_eOut[row];
                eW[r2][i] = s_eRev[row];         // transposed store
                smv[r2][i] = sm[eB[r2][i]];
            } else {
                int e = blockIdx.x*128 + row;
                eB[r2][i] = e; eW[r2][i] = e;
                if (MODE == 2) smv[r2][i] = sm[e];
            }
        }
    #pragma unroll
    for (int c = 0; c < 5; ++c){
        if (c >= myC) continue;
        int h = (c0 + c)*16 + li;
        if (h >= Hc) continue;
        #pragma unroll
        for (int r2 = 0; r2 < 2; ++r2)
            #pragma unroll
            for (int i = 0; i < 4; ++i){
                float v = acc[c][r2][i];
                if (MODE == 0){
                    v = reluf(v);
                } else {
                    v = reluf(v + ib[(size_t)eB[r2][i]*Hc + h]) * smv[r2][i];
                }
                dst[(size_t)eW[r2][i]*Hc + h] = v;
            }
    }
}

// ---------------- K3: agg[bs,m,h] = (sum_n mb[n,m,h]) * sigmoid(max_n mb[n,m,h])
// TLAY=0: standard layout [ (bs,n,m) ][h] (column gather). TLAY=1: transposed [ (bs,m,n) ][h] (linear).
template<int TLAY>
__global__ __launch_bounds__(320) void k_agg(const float* __restrict__ mb,
        float* __restrict__ message_atom, float* __restrict__ agg_out, int final_mode){
    int row = blockIdx.x;           // bs*64 + m
    int bs = row >> 6, m = row & 63;
    int h = threadIdx.x;
    if (h >= Hc) return;
    size_t base, step;
    if (TLAY){ base = ((size_t)(bs*Nc) + m)*(size_t)Nc*Hc + h; step = Hc; }
    else     { base = ((size_t)(bs*Nc)*Nc + m)*(size_t)Hc + h; step = (size_t)Nc*Hc; }
    float s = 0.f, mx = -INFINITY;
    #pragma unroll 8
    for (int n = 0; n < Nc; ++n){
        float v = mb[base + (size_t)n*step];
        s += v; mx = fmaxf(mx, v);
    }
    float agg = s * (1.f/(1.f + expf(-mx)));
    if (final_mode) agg_out[(size_t)row*Hc + h] = agg;
    else message_atom[(size_t)row*Hc + h] += agg;
}

// ---------------- K4: res[n,m] = dot(ma[n],ma[m])*adj[n,m]; sm = softmax over n per (b,s,m)
__global__ __launch_bounds__(256) void k_resonance_softmax(const float* __restrict__ message_atom,
        const float* __restrict__ adj, float* __restrict__ sm){
    int bs = blockIdx.x >> 6, m = blockIdx.x & 63;
    __shared__ float am[Hc];
    __shared__ float res[Nc];
    for (int d = threadIdx.x; d < Hc; d += blockDim.x)
        am[d] = message_atom[((size_t)(bs*Nc)+m)*Hc + d];
    __syncthreads();
    int wave = threadIdx.x >> 6, lane = threadIdx.x & 63;
    for (int n = wave; n < Nc; n += 4){
        const float* man = message_atom + ((size_t)(bs*Nc)+n)*Hc;
        float acc = 0.f;
        for (int d = lane; d < Hc; d += 64) acc = fmaf(man[d], am[d], acc);
        #pragma unroll
        for (int off = 32; off > 0; off >>= 1) acc += __shfl_xor(acc, off, 64);
        if (lane == 0) res[n] = acc * adj[((size_t)(bs*Nc)+n)*Nc + m];
    }
    __syncthreads();
    if (threadIdx.x < Nc){
        float v = res[threadIdx.x];
        float mx = v;
        #pragma unroll
        for (int off = 32; off > 0; off >>= 1) mx = fmaxf(mx, __shfl_xor(mx, off, 64));
        float e = expf(v - mx);
        float ssum = e;
        #pragma unroll
        for (int off = 32; off > 0; off >>= 1) ssum += __shfl_xor(ssum, off, 64);
        sm[((size_t)(bs*Nc)+threadIdx.x)*Nc + m] = e / ssum;
    }
}

// ---------------- K6: atom_hiddens = relu([agg|message_atom|input_atom] @ W_o + b_o)
#define R7 4
__global__ __launch_bounds__(320) void k_output(const float* __restrict__ agg,
        const float* __restrict__ message_atom, const float* __restrict__ input_atom,
        const float* __restrict__ W_o, const float* __restrict__ b_o, float* __restrict__ out){
    __shared__ float xin[R7][3*Hc];
    int r0 = blockIdx.x * R7;
    for (int idx = threadIdx.x; idx < R7*3*Hc; idx += blockDim.x){
        int r = idx / (3*Hc), k = idx - r*(3*Hc);
        int row = r0 + r;
        float v;
        if (k < Hc)           v = agg[(size_t)row*Hc + k];
        else if (k < 2*Hc)    v = message_atom[(size_t)row*Hc + (k - Hc)];
        else                  v = input_atom[(size_t)row*Hc + (k - 2*Hc)];
        xin[r][k] = v;
    }
    __syncthreads();
    int h = threadIdx.x;
    if (h < Hc){
        float acc[R7];
        #pragma unroll
        for (int r=0;r<R7;r++) acc[r] = b_o[h];
        for (int d = 0; d < 3*Hc; ++d){
            float w = W_o[d*Hc + h];
            #pragma unroll
            for (int r=0;r<R7;r++) acc[r] = fmaf(xin[r][d], w, acc[r]);
        }
        #pragma unroll
        for (int r=0;r<R7;r++) out[(size_t)(r0+r)*Hc + h] = reluf(acc[r]);
    }
}

extern "C" void kernel_launch(void* const* d_in, const int* in_sizes, int n_in,
                              void* d_out, int out_size, void* d_ws, size_t ws_size,
                              hipStream_t stream){
    const float* f_atoms  = (const float*)d_in[0];
    const float* f_bonds  = (const float*)d_in[1];
    const float* adj      = (const float*)d_in[2];
    const float* W_i_atom = (const float*)d_in[3];
    const float* W_i_bond = (const float*)d_in[4];
    const float* W_h0     = (const float*)d_in[5];
    const float* W_h1     = (const float*)d_in[6];
    const float* W_o      = (const float*)d_in[7];
    const float* b_o      = (const float*)d_in[8];

    float* out = (float*)d_out;
    float* atom_hiddens = out;                       // [2048, 300]
    float* mb_out = out + (size_t)ROWS*Hc;           // [131072, 300] fp32 (output #2)
    float* mb1T = mb_out;                            // step-1 result, TRANSPOSED, same buffer
                                                     // (step-2 reads/writes row-locally in place)
    float* wsf = (float*)d_ws;
    float* input_atom   = wsf; wsf += (size_t)ROWS*Hc;
    float* message_atom = wsf; wsf += (size_t)ROWS*Hc;
    float* sm           = wsf; wsf += (size_t)EDGES;
    float* ib           = wsf; wsf += (size_t)EDGES*Hc;         // 39.3M floats
    unsigned short* wsu = (unsigned short*)wsf;
    unsigned short* WP0 = wsu; wsu += 10*BSLICE;
    unsigned short* WP1 = wsu; wsu += 10*BSLICE;
    unsigned short* WPb = wsu; wsu += 5*BSLICE;
    float* agg_out = ib;   // alias: ib dead after step-2 GEMM

    k_atom_embed<<<ROWS, 320, 0, stream>>>(f_atoms, W_i_atom, input_atom, message_atom);
    k_prep_all<<<1900, 256, 0, stream>>>(W_h0, W_h1, W_i_bond, WP0, WP1, WPb);
    // bond embed (fused adj*f_bonds): ib = relu((adj*f_bonds) @ W_i_bond)
    k_gemm_t<0><<<EDGES/128, 1024, 0, stream>>>(f_bonds, WPb, nullptr, adj, nullptr, nullptr, ib);
    // step 1: mb_old = ib -> mb1T (pair blocks, transposed store)
    k_agg<0><<<ROWS, 320, 0, stream>>>(ib, message_atom, nullptr, 0);
    k_resonance_softmax<<<ROWS, 256, 0, stream>>>(message_atom, adj, sm);
    k_gemm_t<1><<<BS*32, 1024, 0, stream>>>(ib, WP0, message_atom, adj, sm, ib, mb1T);
    // step 2: mb_old = mb1T -> mb_out (row blocks, direct-row A-read, in-place row-local)
    k_agg<1><<<ROWS, 320, 0, stream>>>(mb1T, message_atom, nullptr, 0);
    k_resonance_softmax<<<ROWS, 256, 0, stream>>>(message_atom, adj, sm);
    k_gemm_t<2><<<EDGES/128, 1024, 0, stream>>>(mb1T, WP1, message_atom, adj, sm, ib, mb_out);
    // final aggregate + output layer
    k_agg<0><<<ROWS, 320, 0, stream>>>(mb_out, nullptr, agg_out, 1);
    k_output<<<ROWS/R7, 320, 0, stream>>>(agg_out, message_atom, input_atom, W_o, b_o, atom_hiddens);
}